// Round 2
// baseline (853.851 us; speedup 1.0000x reference)
//
#include <hip/hip_runtime.h>
#include <cstdint>
#include <cstddef>

#define TT    100
#define MROWS 200      // T*C real rows
#define KDIM  16384    // H*W
#define DDIM  8192     // hypervector dim
#define KSL   8        // K slices (grid.z)
#define KPER  (KDIM / KSL)

typedef __bf16 bf16x8 __attribute__((ext_vector_type(8)));
typedef float  f32x4  __attribute__((ext_vector_type(4)));

static __device__ __forceinline__ unsigned short f2bf_rne(float f) {
    unsigned int u = __float_as_uint(f);
    unsigned int r = (u + 0x7FFFu + ((u >> 16) & 1u)) >> 16;
    return (unsigned short)r;
}
static __device__ __forceinline__ float bf2f(unsigned short s) {
    return __uint_as_float(((unsigned int)s) << 16);
}

// ---------------------------------------------------------------------------
// Zero d_out (it is poisoned 0xAA before every timed launch).
// ---------------------------------------------------------------------------
__global__ __launch_bounds__(256) void zero_kernel(float* __restrict__ out) {
    out[blockIdx.x * 256 + threadIdx.x] = 0.f;
}

// ---------------------------------------------------------------------------
// Fused GEMM + bind-reduce.
//   gesture[d] = sum_{m<200,k} hist[m,k] * pos[k,d] * time_w[m>>1,d] * pol_w[m&1,d]
// A (hist fp32) is split on the fly into hi/lo bf16 planes (exact to ~2^-17
// relative after recombination; pos entries are +/-1 so bf16 B is exact).
// Tile: BM=64 x BN=128 x BK=32, 4 waves, MFMA 16x16x32 bf16.
// Grid (DDIM/128, 4 m-tiles, KSL k-slices); epilogue reduces the C-tile
// against time*pol weights and atomicAdd's one float per column into out[].
// ---------------------------------------------------------------------------
__global__ __launch_bounds__(256) void gemm_kernel(const float* __restrict__ hist,
                                                   const float* __restrict__ pos,
                                                   const float* __restrict__ time_w,
                                                   const float* __restrict__ pol_w,
                                                   float* __restrict__ out) {
    __shared__ alignas(16) unsigned short As[2][64][32];   // [plane][m][k]
    __shared__ alignas(16) unsigned short Bs[128][40];     // [n][k], +8 pad
    __shared__ float sPart[128];

    const int t     = threadIdx.x;
    const int n0    = blockIdx.x * 128;
    const int m0    = blockIdx.y * 64;
    const int kbase = blockIdx.z * KPER;

    const int lane = t & 63;
    const int wv   = t >> 6;
    const int wm   = (wv & 1) * 32;    // wave m offset
    const int wn   = (wv >> 1) * 64;   // wave n offset
    const int l15  = lane & 15;
    const int q8   = (lane >> 4) * 8;  // k offset within fragment

    if (t < 128) sPart[t] = 0.f;       // visible after first __syncthreads

    // A staging: thread -> (row, 8-k group)
    const int ar_  = t >> 2;           // 0..63
    const int akb  = (t & 3) * 8;      // 0,8,16,24
    const int arow = m0 + ar_;
    const bool avalid = arow < MROWS;
    const float* gA = hist + (size_t)arow * KDIM + akb;   // only deref if avalid

    // B staging: thread -> (2 k-rows, 8 consecutive n)
    const int bk2 = (t & 15) * 2;      // 0..30
    const int bnb = (t >> 4) * 8;      // 0..120
    const float* gB0 = pos + ((size_t)kbase + bk2) * DDIM + n0 + bnb;
    const float* gB1 = gB0 + DDIM;

    f32x4 acc[2][4];
#pragma unroll
    for (int s = 0; s < 2; ++s)
#pragma unroll
        for (int j = 0; j < 4; ++j) acc[s][j] = (f32x4){0.f, 0.f, 0.f, 0.f};

    for (int kk = 0; kk < KPER; kk += 32) {
        // global loads first (overlap with prior MFMAs)
        float4 a0 = {0.f, 0.f, 0.f, 0.f}, a1 = {0.f, 0.f, 0.f, 0.f};
        if (avalid) {
            a0 = *(const float4*)(gA + kbase + kk);
            a1 = *(const float4*)(gA + kbase + kk + 4);
        }
        const float* b0 = gB0 + (size_t)kk * DDIM;
        const float* b1 = gB1 + (size_t)kk * DDIM;
        float4 x0 = *(const float4*)(b0);
        float4 x1 = *(const float4*)(b0 + 4);
        float4 y0 = *(const float4*)(b1);
        float4 y1 = *(const float4*)(b1 + 4);

        __syncthreads();   // previous iteration's frag reads done

        {   // A: split to hi/lo bf16, write both planes
            float v[8] = {a0.x, a0.y, a0.z, a0.w, a1.x, a1.y, a1.z, a1.w};
            alignas(16) unsigned short hs[8];
            alignas(16) unsigned short ls[8];
#pragma unroll
            for (int i = 0; i < 8; ++i) {
                unsigned short h = f2bf_rne(v[i]);
                hs[i] = h;
                ls[i] = f2bf_rne(v[i] - bf2f(h));
            }
            *(uint4*)&As[0][ar_][akb] = *(const uint4*)hs;
            *(uint4*)&As[1][ar_][akb] = *(const uint4*)ls;
        }
        {   // B: truncate fp32 +/-1 -> bf16 (exact), transpose into [n][k]
            const float xv[8] = {x0.x, x0.y, x0.z, x0.w, x1.x, x1.y, x1.z, x1.w};
            const float yv[8] = {y0.x, y0.y, y0.z, y0.w, y1.x, y1.y, y1.z, y1.w};
#pragma unroll
            for (int j = 0; j < 8; ++j) {
                unsigned int w = (__float_as_uint(xv[j]) >> 16) |
                                 (__float_as_uint(yv[j]) & 0xFFFF0000u);
                *(unsigned int*)&Bs[bnb + j][bk2] = w;
            }
        }

        __syncthreads();   // tiles visible

        uint4 fa0[2], fa1[2], fb[4];
#pragma unroll
        for (int s = 0; s < 2; ++s) {
            fa0[s] = *(const uint4*)&As[0][wm + s * 16 + l15][q8];
            fa1[s] = *(const uint4*)&As[1][wm + s * 16 + l15][q8];
        }
#pragma unroll
        for (int j = 0; j < 4; ++j)
            fb[j] = *(const uint4*)&Bs[wn + j * 16 + l15][q8];

#pragma unroll
        for (int s = 0; s < 2; ++s)
#pragma unroll
            for (int j = 0; j < 4; ++j) {
                acc[s][j] = __builtin_amdgcn_mfma_f32_16x16x32_bf16(
                    __builtin_bit_cast(bf16x8, fa0[s]),
                    __builtin_bit_cast(bf16x8, fb[j]), acc[s][j], 0, 0, 0);
                acc[s][j] = __builtin_amdgcn_mfma_f32_16x16x32_bf16(
                    __builtin_bit_cast(bf16x8, fa1[s]),
                    __builtin_bit_cast(bf16x8, fb[j]), acc[s][j], 0, 0, 0);
            }
    }

    // Epilogue: C/D layout col = lane&15, row = (lane>>4)*4 + reg (m89/m91).
    // Reduce C-tile over m with weight time_w[t,d]*pol_w[p,d], m = 2t+p.
    const int qrow = (lane >> 4) * 4;
#pragma unroll
    for (int j = 0; j < 4; ++j) {
        const int col = wn + j * 16 + l15;     // 0..127 within tile
        const int d   = n0 + col;
        const float p0 = pol_w[d];
        const float p1 = pol_w[DDIM + d];
        float part = 0.f;
#pragma unroll
        for (int s = 0; s < 2; ++s)
#pragma unroll
            for (int r = 0; r < 4; ++r) {
                const int m = m0 + wm + s * 16 + qrow + r;
                if (m < MROWS) {
                    const int tt_ = m >> 1;
                    const float w = time_w[(size_t)tt_ * DDIM + d] *
                                    ((m & 1) ? p1 : p0);
                    part += w * acc[s][j][r];
                }
            }
        atomicAdd(&sPart[col], part);
    }
    __syncthreads();
    if (t < 128) atomicAdd(out + n0 + t, sPart[t]);
}

// ---------------------------------------------------------------------------
// Final: out[d] = sign(out[d]) in place.
// ---------------------------------------------------------------------------
__global__ __launch_bounds__(256) void sign_kernel(float* __restrict__ out) {
    int d = blockIdx.x * 256 + threadIdx.x;
    float s = out[d];
    out[d] = (s > 0.f) ? 1.f : ((s < 0.f) ? -1.f : 0.f);
}

// ---------------------------------------------------------------------------
extern "C" void kernel_launch(void* const* d_in, const int* in_sizes, int n_in,
                              void* d_out, int out_size, void* d_ws, size_t ws_size,
                              hipStream_t stream) {
    const float* hist   = (const float*)d_in[0];   // [100,2,128,128]
    const float* time_w = (const float*)d_in[1];   // [100,8192]
    const float* pol_w  = (const float*)d_in[2];   // [2,8192]
    const float* pos_w  = (const float*)d_in[3];   // [16384,8192]
    float* out = (float*)d_out;                    // [8192]
    (void)d_ws; (void)ws_size;                     // zero workspace used

    zero_kernel<<<DDIM / 256, 256, 0, stream>>>(out);
    gemm_kernel<<<dim3(DDIM / 128, 4, KSL), 256, 0, stream>>>(hist, pos_w, time_w, pol_w, out);
    sign_kernel<<<DDIM / 256, 256, 0, stream>>>(out);
}

// Round 3
// 768.283 us; speedup vs baseline: 1.1114x; 1.1114x over previous
//
#include <hip/hip_runtime.h>
#include <cstdint>
#include <cstddef>

#define TT    100
#define MROWS 200      // T*C real rows
#define KDIM  16384    // H*W
#define DDIM  8192     // hypervector dim
#define KSL   16       // K slices (grid.z)
#define KPER  (KDIM / KSL)   // 1024

typedef __bf16 bf16x8 __attribute__((ext_vector_type(8)));
typedef float  f32x4  __attribute__((ext_vector_type(4)));

static __device__ __forceinline__ unsigned short f2bf_rne(float f) {
    unsigned int u = __float_as_uint(f);
    unsigned int r = (u + 0x7FFFu + ((u >> 16) & 1u)) >> 16;
    return (unsigned short)r;
}
static __device__ __forceinline__ float bf2f(unsigned short s) {
    return __uint_as_float(((unsigned int)s) << 16);
}

// ---------------------------------------------------------------------------
// Zero d_out (poisoned 0xAA before every timed launch).
// ---------------------------------------------------------------------------
__global__ __launch_bounds__(256) void zero_kernel(float* __restrict__ out) {
    out[blockIdx.x * 256 + threadIdx.x] = 0.f;
}

// ---------------------------------------------------------------------------
// Fused GEMM + bind-reduce, 128x128x32 tile (m93-class structure).
//   gesture[d] = sum_{m<200,k} hist[m,k] * pos[k,d] * time_w[m>>1,d] * pol_w[m&1,d]
// A (hist fp32) split on the fly into hi/lo bf16 planes (recombined product
// exact to ~2^-17 rel); pos entries +/-1 are exact in bf16 (truncation).
// 4 waves in 2x2 grid; each wave: 4x4 frags of 16x16x32, acc[4][4].
// Grid (64 n-blocks, 2 m-blocks, KSL k-slices) = 2048 blocks; epilogue
// reduces the C-tile against time*pol weights, one atomicAdd per column.
// Zero d_ws usage (round-1 ws-based pipeline diverged on replay; stay off).
// ---------------------------------------------------------------------------
__global__ __launch_bounds__(256) void gemm_kernel(const float* __restrict__ hist,
                                                   const float* __restrict__ pos,
                                                   const float* __restrict__ time_w,
                                                   const float* __restrict__ pol_w,
                                                   float* __restrict__ out) {
    __shared__ alignas(16) unsigned short As[2][128][32];  // [plane][m][k] 16 KB
    __shared__ alignas(16) unsigned short Bs[128][40];     // [n][k], +8 pad 10 KB
    __shared__ float sPart[128];

    const int t     = threadIdx.x;
    const int n0    = blockIdx.x * 128;
    const int m0    = blockIdx.y * 128;
    const int kbase = blockIdx.z * KPER;

    const int lane = t & 63;
    const int wv   = t >> 6;
    const int wm   = (wv & 1) * 64;    // wave m offset (2x2 wave grid)
    const int wn   = (wv >> 1) * 64;   // wave n offset
    const int l15  = lane & 15;
    const int q8   = (lane >> 4) * 8;  // k offset within fragment

    if (t < 128) sPart[t] = 0.f;       // visible after first __syncthreads

    // A staging: each thread handles rows (ar, ar+64), 8 consecutive k.
    const int ar  = t >> 2;            // 0..63
    const int akb = (t & 3) * 8;       // 0,8,16,24
    const int rowA0 = m0 + ar;
    const int rowA1 = m0 + ar + 64;
    const bool v0 = rowA0 < MROWS;
    const bool v1 = rowA1 < MROWS;
    const float* gA0 = hist + (size_t)rowA0 * KDIM + akb;
    const float* gA1 = hist + (size_t)rowA1 * KDIM + akb;

    // B staging: thread -> (2 k-rows, 8 consecutive n)  [round-2 map]
    const int bk2 = (t & 15) * 2;      // 0..30
    const int bnb = (t >> 4) * 8;      // 0..120
    const float* gB0 = pos + ((size_t)kbase + bk2) * DDIM + n0 + bnb;
    const float* gB1 = gB0 + DDIM;

    f32x4 acc[4][4];
#pragma unroll
    for (int s = 0; s < 4; ++s)
#pragma unroll
        for (int j = 0; j < 4; ++j) acc[s][j] = (f32x4){0.f, 0.f, 0.f, 0.f};

    for (int kk = 0; kk < KPER; kk += 32) {
        // global loads first (overlap with prior MFMAs)
        float4 a00 = {0,0,0,0}, a01 = {0,0,0,0};
        float4 a10 = {0,0,0,0}, a11 = {0,0,0,0};
        if (v0) { a00 = *(const float4*)(gA0 + kbase + kk);
                  a01 = *(const float4*)(gA0 + kbase + kk + 4); }
        if (v1) { a10 = *(const float4*)(gA1 + kbase + kk);
                  a11 = *(const float4*)(gA1 + kbase + kk + 4); }
        const float* b0 = gB0 + (size_t)kk * DDIM;
        const float* b1 = gB1 + (size_t)kk * DDIM;
        float4 x0 = *(const float4*)(b0);
        float4 x1 = *(const float4*)(b0 + 4);
        float4 y0 = *(const float4*)(b1);
        float4 y1 = *(const float4*)(b1 + 4);

        __syncthreads();   // previous iteration's frag reads done

        {   // A rows: split to hi/lo bf16
            float va[8] = {a00.x, a00.y, a00.z, a00.w, a01.x, a01.y, a01.z, a01.w};
            float vb[8] = {a10.x, a10.y, a10.z, a10.w, a11.x, a11.y, a11.z, a11.w};
            alignas(16) unsigned short h0[8], l0[8], h1[8], l1[8];
#pragma unroll
            for (int i = 0; i < 8; ++i) {
                unsigned short h = f2bf_rne(va[i]);
                h0[i] = h; l0[i] = f2bf_rne(va[i] - bf2f(h));
                unsigned short g = f2bf_rne(vb[i]);
                h1[i] = g; l1[i] = f2bf_rne(vb[i] - bf2f(g));
            }
            *(uint4*)&As[0][ar][akb]      = *(const uint4*)h0;
            *(uint4*)&As[1][ar][akb]      = *(const uint4*)l0;
            *(uint4*)&As[0][ar + 64][akb] = *(const uint4*)h1;
            *(uint4*)&As[1][ar + 64][akb] = *(const uint4*)l1;
        }
        {   // B: truncate fp32 +/-1 -> bf16 (exact), transpose into [n][k]
            const float xv[8] = {x0.x, x0.y, x0.z, x0.w, x1.x, x1.y, x1.z, x1.w};
            const float yv[8] = {y0.x, y0.y, y0.z, y0.w, y1.x, y1.y, y1.z, y1.w};
#pragma unroll
            for (int j = 0; j < 8; ++j) {
                unsigned int w = (__float_as_uint(xv[j]) >> 16) |
                                 (__float_as_uint(yv[j]) & 0xFFFF0000u);
                *(unsigned int*)&Bs[bnb + j][bk2] = w;
            }
        }

        __syncthreads();   // tiles visible

        uint4 fa0[4], fa1[4], fb[4];
#pragma unroll
        for (int s = 0; s < 4; ++s) {
            fa0[s] = *(const uint4*)&As[0][wm + s * 16 + l15][q8];
            fa1[s] = *(const uint4*)&As[1][wm + s * 16 + l15][q8];
        }
#pragma unroll
        for (int j = 0; j < 4; ++j)
            fb[j] = *(const uint4*)&Bs[wn + j * 16 + l15][q8];

#pragma unroll
        for (int s = 0; s < 4; ++s)
#pragma unroll
            for (int j = 0; j < 4; ++j) {
                acc[s][j] = __builtin_amdgcn_mfma_f32_16x16x32_bf16(
                    __builtin_bit_cast(bf16x8, fa0[s]),
                    __builtin_bit_cast(bf16x8, fb[j]), acc[s][j], 0, 0, 0);
                acc[s][j] = __builtin_amdgcn_mfma_f32_16x16x32_bf16(
                    __builtin_bit_cast(bf16x8, fa1[s]),
                    __builtin_bit_cast(bf16x8, fb[j]), acc[s][j], 0, 0, 0);
            }
    }

    // Epilogue: C/D layout col = lane&15, row = (lane>>4)*4 + reg (m89/m91).
    // Reduce C-tile over m with weight time_w[t,d]*pol_w[p,d], m = 2t+p.
    const int qrow = (lane >> 4) * 4;
#pragma unroll
    for (int j = 0; j < 4; ++j) {
        const int col = wn + j * 16 + l15;     // 0..127 within tile
        const int d   = n0 + col;
        const float p0 = pol_w[d];
        const float p1 = pol_w[DDIM + d];
        float part = 0.f;
#pragma unroll
        for (int s = 0; s < 4; ++s)
#pragma unroll
            for (int r = 0; r < 4; ++r) {
                const int m = m0 + wm + s * 16 + qrow + r;
                if (m < MROWS) {
                    const int tt_ = m >> 1;
                    const float w = time_w[(size_t)tt_ * DDIM + d] *
                                    ((m & 1) ? p1 : p0);
                    part += w * acc[s][j][r];
                }
            }
        atomicAdd(&sPart[col], part);
    }
    __syncthreads();
    if (t < 128) atomicAdd(out + n0 + t, sPart[t]);
}

// ---------------------------------------------------------------------------
// Final: out[d] = sign(out[d]) in place.
// ---------------------------------------------------------------------------
__global__ __launch_bounds__(256) void sign_kernel(float* __restrict__ out) {
    int d = blockIdx.x * 256 + threadIdx.x;
    float s = out[d];
    out[d] = (s > 0.f) ? 1.f : ((s < 0.f) ? -1.f : 0.f);
}

// ---------------------------------------------------------------------------
extern "C" void kernel_launch(void* const* d_in, const int* in_sizes, int n_in,
                              void* d_out, int out_size, void* d_ws, size_t ws_size,
                              hipStream_t stream) {
    const float* hist   = (const float*)d_in[0];   // [100,2,128,128]
    const float* time_w = (const float*)d_in[1];   // [100,8192]
    const float* pol_w  = (const float*)d_in[2];   // [2,8192]
    const float* pos_w  = (const float*)d_in[3];   // [16384,8192]
    float* out = (float*)d_out;                    // [8192]
    (void)d_ws; (void)ws_size;                     // zero workspace used

    zero_kernel<<<DDIM / 256, 256, 0, stream>>>(out);
    gemm_kernel<<<dim3(DDIM / 128, 2, KSL), 256, 0, stream>>>(hist, pos_w, time_w, pol_w, out);
    sign_kernel<<<DDIM / 256, 256, 0, stream>>>(out);
}